// Round 9
// baseline (2062.711 us; speedup 1.0000x reference)
//
#include <hip/hip_runtime.h>
#include <cstdint>
#include <cstddef>

typedef __bf16 bf16_t;
typedef __bf16 bf16x8 __attribute__((ext_vector_type(8)));
typedef float f32x4 __attribute__((ext_vector_type(4)));
typedef int i32x4 __attribute__((ext_vector_type(4)));
typedef short short4v __attribute__((ext_vector_type(4)));

#define B_ 4
#define T_ 1024
#define C_ 1024
#define H_ 16
#define L_ 6
#define V_ 32000
#define M_ (B_ * T_)   // 4096

// ---------------------------------------------------------------- embedding
__global__ __launch_bounds__(256) void k_embed(const int* __restrict__ idx,
                                               const float* __restrict__ tok,
                                               const float* __restrict__ pos,
                                               float* __restrict__ x) {
  int row = blockIdx.x;            // b*T + t
  int t = row & (T_ - 1);
  int id = idx[row];
  int c = threadIdx.x * 4;
  f32x4 a = *(const f32x4*)(tok + (size_t)id * C_ + c);
  f32x4 p = *(const f32x4*)(pos + (size_t)t * C_ + c);
  *(f32x4*)(x + (size_t)row * C_ + c) = a + p;
}

// ---------------------------------------------------------------- layernorm (f32 in -> bf16 out)
__global__ __launch_bounds__(256) void k_ln(const float* __restrict__ x,
                                            const float* __restrict__ w,
                                            const float* __restrict__ b,
                                            bf16_t* __restrict__ out) {
  __shared__ float red[8];
  int row = blockIdx.x;
  int tid = threadIdx.x;
  const float* xr = x + (size_t)row * C_;
  f32x4 v = *(const f32x4*)(xr + tid * 4);
  float s = v[0] + v[1] + v[2] + v[3];
  float q = v[0] * v[0] + v[1] * v[1] + v[2] * v[2] + v[3] * v[3];
#pragma unroll
  for (int off = 32; off; off >>= 1) {
    s += __shfl_xor(s, off);
    q += __shfl_xor(q, off);
  }
  int wid = tid >> 6;
  if ((tid & 63) == 0) { red[wid * 2] = s; red[wid * 2 + 1] = q; }
  __syncthreads();
  s = red[0] + red[2] + red[4] + red[6];
  q = red[1] + red[3] + red[5] + red[7];
  float mu = s * (1.f / C_);
  float var = q * (1.f / C_) - mu * mu;
  float rstd = rsqrtf(var + 1e-5f);
  f32x4 wv = *(const f32x4*)(w + tid * 4);
  f32x4 bv = *(const f32x4*)(b + tid * 4);
  bf16_t* o = out + (size_t)row * C_ + tid * 4;
#pragma unroll
  for (int j = 0; j < 4; j++) o[j] = (bf16_t)((v[j] - mu) * rstd * wv[j] + bv[j]);
}

// ------------------------------------------------- head transpose f32 [K][N] -> bf16 [N][K]
__global__ __launch_bounds__(256) void k_transpose_bf16(const float* __restrict__ in,
                                                        bf16_t* __restrict__ out,
                                                        int K, int N) {
  __shared__ float tile[32][33];
  int n0 = blockIdx.x * 32, k0 = blockIdx.y * 32;
  int tid = threadIdx.x;
  int cr = tid >> 5, cc = tid & 31;
#pragma unroll
  for (int it = 0; it < 4; it++) {
    int r = it * 8 + cr;
    tile[r][cc] = in[(size_t)(k0 + r) * N + n0 + cc];
  }
  __syncthreads();
#pragma unroll
  for (int it = 0; it < 4; it++) {
    int r = it * 8 + cr;                       // local n
    out[(size_t)(n0 + r) * K + k0 + cc] = (bf16_t)tile[cc][r];
  }
}

// ------------------------------------------------- fused per-layer weight transpose
__global__ __launch_bounds__(256) void k_transpose_layer(
    const float* __restrict__ qkvw, const float* __restrict__ attnw,
    const float* __restrict__ fc1w, const float* __restrict__ fc2w,
    bf16_t* __restrict__ qkvT, bf16_t* __restrict__ owT,
    bf16_t* __restrict__ fc1T, bf16_t* __restrict__ fc2T) {
  __shared__ float tile[32][33];
  int tb = blockIdx.x;
  const float* in;
  bf16_t* out;
  int K, N;
  bool qs = false;
  if (tb < 3072) { in = qkvw; out = qkvT; K = 1024; N = 3072; qs = true; }
  else if (tb < 4096) { tb -= 3072; in = attnw; out = owT; K = 1024; N = 1024; }
  else if (tb < 8192) { tb -= 4096; in = fc1w; out = fc1T; K = 1024; N = 4096; }
  else { tb -= 8192; in = fc2w; out = fc2T; K = 4096; N = 1024; }
  int nTx = N >> 5;
  int n0 = (tb % nTx) * 32, k0 = (tb / nTx) * 32;
  int tid = threadIdx.x;
  int cr = tid >> 5, cc = tid & 31;
#pragma unroll
  for (int it = 0; it < 4; it++) {
    int r = it * 8 + cr;
    tile[r][cc] = in[(size_t)(k0 + r) * N + n0 + cc];
  }
  __syncthreads();
#pragma unroll
  for (int it = 0; it < 4; it++) {
    int r = it * 8 + cr;                       // local n
    float v = tile[cc][r];
    if (qs && (n0 + r) < 1024) v *= 0.125f;    // fold 1/sqrt(D) into Wq
    out[(size_t)(n0 + r) * K + k0 + cc] = (bf16_t)v;
  }
}

// ---------------------------------------------------------------- flash attention, KVBLK=64
__global__ __launch_bounds__(256) void k_attn(const bf16_t* __restrict__ qh,
                                              const bf16_t* __restrict__ kh,
                                              const bf16_t* __restrict__ vT,
                                              bf16_t* __restrict__ outb) {
  __shared__ bf16_t p_lds[4][16 * 72];   // row stride 72 elem (144B): b128 reads 2-way
  int tid = threadIdx.x, lane = tid & 63, wid = tid >> 6;
  int bh = blockIdx.x;
  int b = bh >> 4, h = bh & (H_ - 1);
  int qbase = blockIdx.y * 64 + wid * 16;
  const bf16_t* qp = qh + ((size_t)bh * T_ + qbase) * 64;
  const bf16_t* kp = kh + (size_t)bh * T_ * 64;
  const bf16_t* vp = vT + (size_t)bh * 64 * T_;
  int r = lane & 15, g = lane >> 4;

  bf16x8 qf0 = *(const bf16x8*)(qp + r * 64 + g * 8);
  bf16x8 qf1 = *(const bf16x8*)(qp + r * 64 + 32 + g * 8);

  f32x4 o[4];
  float m[4], l[4];
#pragma unroll
  for (int j = 0; j < 4; j++) { m[j] = -1e30f; l[j] = 0.f; o[j] = (f32x4){0.f, 0.f, 0.f, 0.f}; }

  int kv_end = qbase + 16;
  for (int jb = 0; jb < kv_end; jb += 64) {
    f32x4 s[4];
#pragma unroll
    for (int t = 0; t < 4; t++) s[t] = (f32x4){0.f, 0.f, 0.f, 0.f};
    const bf16_t* kb = kp + (size_t)(jb + r) * 64 + g * 8;
#pragma unroll
    for (int t = 0; t < 4; t++) {
      const bf16_t* kt = kb + (size_t)t * 16 * 64;
      s[t] = __builtin_amdgcn_mfma_f32_16x16x32_bf16(qf0, *(const bf16x8*)(kt), s[t], 0, 0, 0);
      s[t] = __builtin_amdgcn_mfma_f32_16x16x32_bf16(qf1, *(const bf16x8*)(kt + 32), s[t], 0, 0, 0);
    }

    bool needMask = (jb + 63 > qbase);   // wave-uniform; skip cndmask when fully causal
    float pv[4][4], fac[4];
#pragma unroll
    for (int j = 0; j < 4; j++) {
      int rowg = qbase + g * 4 + j;
      float v0 = s[0][j], v1 = s[1][j], v2 = s[2][j], v3 = s[3][j];
      if (needMask) {
        if (jb + r > rowg) v0 = -1e30f;
        if (jb + 16 + r > rowg) v1 = -1e30f;
        if (jb + 32 + r > rowg) v2 = -1e30f;
        if (jb + 48 + r > rowg) v3 = -1e30f;
      }
      float t0 = fmaxf(fmaxf(v0, v1), fmaxf(v2, v3));
      t0 = fmaxf(t0, __shfl_xor(t0, 1));
      t0 = fmaxf(t0, __shfl_xor(t0, 2));
      t0 = fmaxf(t0, __shfl_xor(t0, 4));
      t0 = fmaxf(t0, __shfl_xor(t0, 8));
      float nm = fmaxf(m[j], t0);
      pv[j][0] = __expf(v0 - nm);
      pv[j][1] = __expf(v1 - nm);
      pv[j][2] = __expf(v2 - nm);
      pv[j][3] = __expf(v3 - nm);
      float f = __expf(m[j] - nm);
      float ts = (pv[j][0] + pv[j][1]) + (pv[j][2] + pv[j][3]);
      ts += __shfl_xor(ts, 1);
      ts += __shfl_xor(ts, 2);
      ts += __shfl_xor(ts, 4);
      ts += __shfl_xor(ts, 8);
      l[j] = l[j] * f + ts;
      m[j] = nm;
      fac[j] = f;
    }
    f32x4 fv = (f32x4){fac[0], fac[1], fac[2], fac[3]};
#pragma unroll
    for (int d = 0; d < 4; d++) o[d] *= fv;

    bf16_t* pl = p_lds[wid];
#pragma unroll
    for (int j = 0; j < 4; j++)
#pragma unroll
      for (int t = 0; t < 4; t++)
        pl[(g * 4 + j) * 72 + t * 16 + r] = (bf16_t)pv[j][t];

    bf16x8 pa0 = *(const bf16x8*)(pl + r * 72 + g * 8);
    bf16x8 pa1 = *(const bf16x8*)(pl + r * 72 + 32 + g * 8);
#pragma unroll
    for (int d = 0; d < 4; d++) {
      const bf16_t* vf = vp + (size_t)(d * 16 + r) * T_ + jb + g * 8;
      o[d] = __builtin_amdgcn_mfma_f32_16x16x32_bf16(pa0, *(const bf16x8*)(vf), o[d], 0, 0, 0);
      o[d] = __builtin_amdgcn_mfma_f32_16x16x32_bf16(pa1, *(const bf16x8*)(vf + 32), o[d], 0, 0, 0);
    }
  }

#pragma unroll
  for (int d = 0; d < 4; d++) {
#pragma unroll
    for (int j = 0; j < 4; j++) {
      float val = o[d][j] / l[j];
      outb[((size_t)(b * T_ + qbase + g * 4 + j)) * C_ + h * 64 + d * 16 + r] = (bf16_t)val;
    }
  }
}

// ---------------------------------------------------------------- shared helpers
__device__ __forceinline__ void gld_lds16(const bf16_t* g, bf16_t* l) {
  __builtin_amdgcn_global_load_lds((const __attribute__((address_space(1))) void*)g,
                                   (__attribute__((address_space(3))) void*)l, 16, 0, 0);
}
__device__ __forceinline__ bf16x8 lds_rd128(uint32_t addr) {
  i32x4 d;
  asm volatile("ds_read_b128 %0, %1" : "=v"(d) : "v"(addr));
  return __builtin_bit_cast(bf16x8, d);
}
#define BAR_() __builtin_amdgcn_s_barrier()
#define SCHED0_() __builtin_amdgcn_sched_barrier(0)
#define WLGN_(n)                                                           \
  do {                                                                     \
    asm volatile("s_waitcnt lgkmcnt(" #n ")" ::: "memory");                \
    SCHED0_();                                                             \
  } while (0)

// ---------------------------------------------------------------- 128x128 pipelined GEMM
// MODE: 0 = f32 out, 1 = bf16 out, 2 = qkv-split (q,k [bh][t][d]; v -> vT [bh][d][t]).
template <int MODE, int HASB, int HASRELU, int HASRES>
__global__ __launch_bounds__(256, 2) void k_gemm(const bf16_t* __restrict__ A,
                                                 const bf16_t* __restrict__ Bt,
                                                 const float* __restrict__ bias,
                                                 const float* resid,
                                                 void* Cout, int M, int N, int K) {
  __shared__ bf16_t As[2][128][64];
  __shared__ bf16_t Bs[2][128][64];
  bf16_t* AsF = &As[0][0][0];
  bf16_t* BsF = &Bs[0][0][0];
  const uint32_t asb = (uint32_t)(uintptr_t)AsF;
  const uint32_t bsb = (uint32_t)(uintptr_t)BsF;

  int tid = threadIdx.x, lane = tid & 63, w = tid >> 6;
  int wr = w >> 1, wc = w & 1;
  int r15 = lane & 15, g4 = lane >> 4;

  int nwg = (int)(gridDim.x * gridDim.y);
  int bid = (int)(blockIdx.y * gridDim.x + blockIdx.x);
  int xcd = bid & 7, loc = bid >> 3;
  int q8 = nwg >> 3, r8 = nwg & 7;
  int swz = (xcd < r8) ? xcd * (q8 + 1) + loc : r8 * (q8 + 1) + (xcd - r8) * q8 + loc;
  int nY = M >> 7;
  int by = swz % nY, bx = swz / nY;
  size_t rowBase = (size_t)by * 128;
  size_t colBase = (size_t)bx * 128;

  int srowL = (lane >> 3);
  int scol = ((lane & 7) ^ srowL) * 8;

  uint32_t xm = (uint32_t)((r15 & 7) << 4);
  uint32_t offK0 = ((uint32_t)(g4 * 16)) ^ xm;
  uint32_t offK1 = ((uint32_t)(g4 * 16 + 64)) ^ xm;
  uint32_t aRd = asb + (uint32_t)((wr * 64 + r15) * 128);
  uint32_t bRd = bsb + (uint32_t)((wc * 64 + r15) * 128);

  f32x4 acc[4][4];
#pragma unroll
  for (int i = 0; i < 4; i++)
#pragma unroll
    for (int j = 0; j < 4; j++) acc[i][j] = (f32x4){0.f, 0.f, 0.f, 0.f};

  bf16x8 a0[4], a1[4], b0[4], b1[4];

#define KSTAGE_(tk, bufv)                                                            \
  do {                                                                               \
    _Pragma("unroll") for (int _q = 0; _q < 4; _q++) {                               \
      int _row = _q * 32 + w * 8 + srowL;                                            \
      const bf16_t* _ga = A + (rowBase + _row) * (size_t)K + (size_t)(tk)*64 + scol; \
      const bf16_t* _gb = Bt + (colBase + _row) * (size_t)K + (size_t)(tk)*64 + scol;\
      gld_lds16(_ga, AsF + (bufv)*8192 + _q * 2048 + w * 512);                       \
      gld_lds16(_gb, BsF + (bufv)*8192 + _q * 2048 + w * 512);                       \
    }                                                                                \
  } while (0)

#define KRDS_(aset, bset, kk, bufv)                                                  \
  do {                                                                               \
    uint32_t _off = (kk) ? offK1 : offK0;                                            \
    uint32_t _ab = aRd + (uint32_t)(bufv)*16384u + _off;                             \
    uint32_t _bb = bRd + (uint32_t)(bufv)*16384u + _off;                             \
    _Pragma("unroll") for (int _m = 0; _m < 4; _m++)                                 \
        aset[_m] = lds_rd128(_ab + _m * 2048);                                       \
    _Pragma("unroll") for (int _n = 0; _n < 4; _n++)                                 \
        bset[_n] = lds_rd128(_bb + _n * 2048);                                       \
  } while (0)

#define KMFH_(aset, bset)                                                            \
  do {                                                                               \
    __builtin_amdgcn_s_setprio(1);                                                   \
    _Pragma("unroll") for (int _m = 0; _m < 4; _m++)                                 \
        _Pragma("unroll") for (int _n = 0; _n < 4; _n++)                             \
            acc[_m][_n] = __builtin_amdgcn_mfma_f32_16x16x32_bf16(                   \
                aset[_m], bset[_n], acc[_m][_n], 0, 0, 0);                           \
    __builtin_amdgcn_s_setprio(0);                                                   \
  } while (0)

  KSTAGE_(0, 0);
  asm volatile("s_waitcnt vmcnt(0)" ::: "memory");
  BAR_();

  int NT = K >> 6;
  for (int kt = 0; kt < NT; ++kt) {
    int buf = kt & 1;
    bool pf = (kt + 1 < NT);
    if (pf) KSTAGE_(kt + 1, buf ^ 1);
    KRDS_(a0, b0, 0, buf);
    KRDS_(a1, b1, 1, buf);
    WLGN_(8);
    KMFH_(a0, b0);
    WLGN_(0);
    KMFH_(a1, b1);
    asm volatile("s_waitcnt vmcnt(0)" ::: "memory");
    BAR_();
  }

#pragma unroll
  for (int i = 0; i < 4; i++) {
    size_t row0 = rowBase + wr * 64 + i * 16 + g4 * 4;
#pragma unroll
    for (int j = 0; j < 4; j++) {
      size_t col = colBase + wc * 64 + j * 16 + r15;
      float bi = HASB ? bias[col] : 0.f;
      if (MODE == 2) {
        float vv[4];
#pragma unroll
        for (int q = 0; q < 4; q++) vv[q] = acc[i][j][q];
        int part = (int)(col >> 10);
        int within = (int)col & 1023;
        int hh = within >> 6, dd = within & 63;
        int bb = (int)(row0 >> 10), tt = (int)row0 & 1023;
        size_t bhh = (size_t)(bb * 16 + hh);
        if (part < 2) {
          bf16_t* dstp = (bf16_t*)Cout + (size_t)part * ((size_t)M_ * C_);
#pragma unroll
          for (int q = 0; q < 4; q++)
            dstp[(bhh * 1024 + tt + q) * 64 + dd] = (bf16_t)vv[q];
        } else {
          bf16_t* dstp = (bf16_t*)Cout + 2 * ((size_t)M_ * C_);
          short4v pk;
#pragma unroll
          for (int q = 0; q < 4; q++) {
            bf16_t bv = (bf16_t)vv[q];
            pk[q] = __builtin_bit_cast(short, bv);
          }
          *(short4v*)(dstp + (bhh * 64 + dd) * 1024 + tt) = pk;
        }
      } else {
#pragma unroll
        for (int q = 0; q < 4; q++) {
          size_t row = row0 + q;
          float v = acc[i][j][q] + bi;
          if (HASRELU) v = fmaxf(v, 0.f);
          if (HASRES) v += resid[row * (size_t)N + col];
          if (MODE == 1)
            ((bf16_t*)Cout)[row * (size_t)N + col] = (bf16_t)v;
          else
            ((float*)Cout)[row * (size_t)N + col] = v;
        }
      }
    }
  }
#undef KSTAGE_
#undef KRDS_
#undef KMFH_
}

// ---------------------------------------------------------------- 256x256 pipelined GEMM (head)
#define STAGE_(q, tk, bufv)                                                           \
  do {                                                                                \
    const bf16_t* _ga = A + (size_t)(rowBase + (q)*64 + srow) * (size_t)K +           \
                        (size_t)(tk)*64 + scol;                                       \
    const bf16_t* _gb = Bt + (size_t)(colBase + (q)*64 + srow) * (size_t)K +          \
                        (size_t)(tk)*64 + scol;                                       \
    gld_lds16(_ga, AsF + (bufv)*16384 + (q)*4096 + w * 512);                          \
    gld_lds16(_gb, BsF + (bufv)*16384 + (q)*4096 + w * 512);                          \
  } while (0)

#define RDS_(aset, bset, kk, bufv)                                                    \
  do {                                                                                \
    uint32_t _off = (kk) ? offK1 : offK0;                                             \
    uint32_t _ab = aRd + (uint32_t)(bufv)*32768u + _off;                              \
    uint32_t _bb = bRd + (uint32_t)(bufv)*32768u + _off;                              \
    _Pragma("unroll") for (int _m = 0; _m < 8; _m++)                                  \
        aset[_m] = lds_rd128(_ab + _m * 2048);                                        \
    _Pragma("unroll") for (int _n = 0; _n < 4; _n++)                                  \
        bset[_n] = lds_rd128(_bb + _n * 2048);                                        \
  } while (0)

#define MFH_(aset, bset)                                                              \
  do {                                                                                \
    __builtin_amdgcn_s_setprio(1);                                                    \
    _Pragma("unroll") for (int _m = 0; _m < 8; _m++)                                  \
        _Pragma("unroll") for (int _n = 0; _n < 4; _n++)                              \
            acc[_m][_n] = __builtin_amdgcn_mfma_f32_16x16x32_bf16(                    \
                aset[_m], bset[_n], acc[_m][_n], 0, 0, 0);                            \
    __builtin_amdgcn_s_setprio(0);                                                    \
  } while (0)

template <int OUTBF, int HASB, int HASRELU, int HASRES>
__global__ __launch_bounds__(512, 2) void k_gemm256(const bf16_t* __restrict__ A,
                                                    const bf16_t* __restrict__ Bt,
                                                    const float* __restrict__ bias,
                                                    const float* resid,
                                                    void* Cout, int M, int N, int K) {
  __shared__ bf16_t As[2][256][64];
  __shared__ bf16_t Bs[2][256][64];
  bf16_t* AsF = &As[0][0][0];
  bf16_t* BsF = &Bs[0][0][0];
  const uint32_t asb = (uint32_t)(uintptr_t)AsF;
  const uint32_t bsb = (uint32_t)(uintptr_t)BsF;

  int tid = threadIdx.x, lane = tid & 63, w = tid >> 6;
  int wr = w >> 2, wc = w & 3;
  int r15 = lane & 15, g4 = lane >> 4;

  int nwg = (int)gridDim.x;
  int bid = (int)blockIdx.x;
  int xcd = bid & 7, loc = bid >> 3;
  int q8 = nwg >> 3, r8 = nwg & 7;
  int swz = (xcd < r8) ? xcd * (q8 + 1) + loc : r8 * (q8 + 1) + (xcd - r8) * q8 + loc;
  int nY = M >> 8;
  int by = swz % nY, bx = swz / nY;
  int rowBase = by * 256, colBase = bx * 256;

  int srow = w * 8 + (lane >> 3);
  int scol = ((lane & 7) ^ (lane >> 3)) * 8;

  uint32_t xm = (uint32_t)((r15 & 7) << 4);
  uint32_t offK0 = ((uint32_t)(g4 * 16)) ^ xm;
  uint32_t offK1 = ((uint32_t)(g4 * 16 + 64)) ^ xm;
  uint32_t aRd = asb + (uint32_t)((wr * 128 + r15) * 128);
  uint32_t bRd = bsb + (uint32_t)((wc * 64 + r15) * 128);

  f32x4 acc[8][4];
#pragma unroll
  for (int i = 0; i < 8; i++)
#pragma unroll
    for (int j = 0; j < 4; j++) acc[i][j] = (f32x4){0.f, 0.f, 0.f, 0.f};

  bf16x8 a0[8], a1[8], b0[4], b1[4];

#pragma unroll
  for (int q = 0; q < 4; q++) STAGE_(q, 0, 0);
  asm volatile("s_waitcnt vmcnt(0)" ::: "memory");
  BAR_();

  int NT = K >> 6;
  for (int kt = 0; kt < NT; ++kt) {
    int buf = kt & 1;
    bool pf = (kt + 1 < NT);
    if (pf) {
#pragma unroll
      for (int q = 0; q < 4; q++) STAGE_(q, kt + 1, buf ^ 1);
    }
    RDS_(a0, b0, 0, buf);
    RDS_(a1, b1, 1, buf);
    WLGN_(12);
    MFH_(a0, b0);
    WLGN_(0);
    MFH_(a1, b1);
    asm volatile("s_waitcnt vmcnt(0)" ::: "memory");
    BAR_();
  }

#pragma unroll
  for (int m = 0; m < 8; m++) {
    size_t row0 = (size_t)rowBase + wr * 128 + m * 16 + g4 * 4;
#pragma unroll
    for (int n = 0; n < 4; n++) {
      size_t col = (size_t)colBase + wc * 64 + n * 16 + r15;
      float bi = HASB ? bias[col] : 0.f;
#pragma unroll
      for (int qq = 0; qq < 4; qq++) {
        size_t row = row0 + qq;
        float v = acc[m][n][qq] + bi;
        if (HASRELU) v = fmaxf(v, 0.f);
        if (HASRES) v += resid[row * (size_t)N + col];
        if (OUTBF)
          ((bf16_t*)Cout)[row * (size_t)N + col] = (bf16_t)v;
        else
          ((float*)Cout)[row * (size_t)N + col] = v;
      }
    }
  }
}

// ---------------------------------------------------------------- launch
extern "C" void kernel_launch(void* const* d_in, const int* in_sizes, int n_in,
                              void* d_out, int out_size, void* d_ws, size_t ws_size,
                              hipStream_t stream) {
  (void)in_sizes; (void)n_in; (void)out_size; (void)ws_size;
  const int* idx = (const int*)d_in[0];
  const float* tok_emb = (const float*)d_in[1];
  const float* pos_emb = (const float*)d_in[2];
  const float* qkv_w = (const float*)d_in[3];
  const float* attn_out_w = (const float*)d_in[4];
  const float* attn_out_b = (const float*)d_in[5];
  const float* fc1_w = (const float*)d_in[6];
  const float* fc1_b = (const float*)d_in[7];
  const float* fc2_w = (const float*)d_in[8];
  const float* fc2_b = (const float*)d_in[9];
  const float* ln1_w = (const float*)d_in[10];
  const float* ln1_b = (const float*)d_in[11];
  const float* ln2_w = (const float*)d_in[12];
  const float* ln2_b = (const float*)d_in[13];
  const float* lnf_w = (const float*)d_in[14];
  const float* lnf_b = (const float*)d_in[15];
  const float* head_w = (const float*)d_in[16];
  float* out = (float*)d_out;

  char* wsp = (char*)d_ws;
  auto alloc = [&](size_t bytes) {
    char* p = wsp;
    wsp += (bytes + 255) & ~(size_t)255;
    return p;
  };
  float* x      = (float*)alloc((size_t)M_ * C_ * 4);
  bf16_t* hbuf  = (bf16_t*)alloc((size_t)M_ * C_ * 2);
  bf16_t* qhb   = (bf16_t*)alloc((size_t)3 * M_ * C_ * 2);   // q,k,(vT) contiguous
  bf16_t* khb   = qhb + (size_t)M_ * C_;
  bf16_t* vTb   = khb + (size_t)M_ * C_;
  bf16_t* attnb = (bf16_t*)alloc((size_t)M_ * C_ * 2);
  bf16_t* midb  = (bf16_t*)alloc((size_t)M_ * 4 * C_ * 2);
  bf16_t* qkvwT = (bf16_t*)alloc((size_t)3 * C_ * C_ * 2);
  bf16_t* owT   = (bf16_t*)alloc((size_t)C_ * C_ * 2);
  bf16_t* fc1wT = (bf16_t*)alloc((size_t)4 * C_ * C_ * 2);
  bf16_t* fc2wT = (bf16_t*)alloc((size_t)4 * C_ * C_ * 2);
  bf16_t* headwT= (bf16_t*)alloc((size_t)C_ * V_ * 2);

  k_embed<<<M_, 256, 0, stream>>>(idx, tok_emb, pos_emb, x);
  k_transpose_bf16<<<dim3(V_ / 32, C_ / 32), 256, 0, stream>>>(head_w, headwT, C_, V_);

  for (int l = 0; l < L_; l++) {
    k_transpose_layer<<<12288, 256, 0, stream>>>(
        qkv_w + (size_t)l * C_ * 3 * C_, attn_out_w + (size_t)l * C_ * C_,
        fc1_w + (size_t)l * C_ * 4 * C_, fc2_w + (size_t)l * 4 * C_ * C_,
        qkvwT, owT, fc1wT, fc2wT);

    k_ln<<<M_, 256, 0, stream>>>(x, ln1_w + l * C_, ln1_b + l * C_, hbuf);
    k_gemm<2, 0, 0, 0><<<dim3(3 * C_ / 128, M_ / 128), 256, 0, stream>>>(
        hbuf, qkvwT, nullptr, nullptr, qhb, M_, 3 * C_, C_);
    k_attn<<<dim3(B_ * H_, T_ / 64), 256, 0, stream>>>(qhb, khb, vTb, attnb);
    k_gemm<0, 1, 0, 1><<<dim3(C_ / 128, M_ / 128), 256, 0, stream>>>(
        attnb, owT, attn_out_b + l * C_, x, x, M_, C_, C_);

    k_ln<<<M_, 256, 0, stream>>>(x, ln2_w + l * C_, ln2_b + l * C_, hbuf);
    k_gemm<1, 1, 1, 0><<<dim3(4 * C_ / 128, M_ / 128), 256, 0, stream>>>(
        hbuf, fc1wT, fc1_b + (size_t)l * 4 * C_, nullptr, midb, M_, 4 * C_, C_);
    k_gemm<0, 1, 0, 1><<<dim3(C_ / 128, M_ / 128), 256, 0, stream>>>(
        midb, fc2wT, fc2_b + l * C_, x, x, M_, C_, 4 * C_);
  }

  k_ln<<<M_, 256, 0, stream>>>(x, lnf_w, lnf_b, hbuf);
  k_gemm256<0, 0, 0, 0><<<dim3((V_ / 256) * (M_ / 256)), 512, 0, stream>>>(
      hbuf, headwT, nullptr, nullptr, out, M_, V_, C_);
}